// Round 1
// baseline (2203.972 us; speedup 1.0000x reference)
//
#include <hip/hip_runtime.h>
#include <hip/hip_bf16.h>

#define Bb 8
#define Tt 600
#define Cc 8
#define Ff 257
#define TAPS 5
#define DELAY 3
#define KC 40            // TAPS*C
#define NC 48            // KC + C (R columns | P columns)
#define TQ 593           // T - DELAY - TAPS + 1
#define TP 601           // padded LDS stride for Y (odd -> bank-spread)
#define EPSF 1e-10f
#define NTOT (Bb*Tt*Cc*Ff)   // 9,868,800

__device__ __forceinline__ float2 cmul2(float2 a, float2 b) {
  return make_float2(a.x*b.x - a.y*b.y, a.x*b.y + a.y*b.x);
}

// (B,T,C,F) re/im planes -> (B,F,C,T) interleaved float2
__global__ __launch_bounds__(256) void k_tin(const float* __restrict__ in_re,
                                             const float* __restrict__ in_im,
                                             float2* __restrict__ Yt) {
  __shared__ float2 tile[32][33];
  int f0 = blockIdx.x * 32, t0 = blockIdx.y * 32;
  int b = blockIdx.z >> 3, c = blockIdx.z & 7;
  int tx = threadIdx.x & 31, ty = threadIdx.x >> 5;
#pragma unroll
  for (int ii = 0; ii < 4; ++ii) {
    int t = t0 + ty + 8 * ii, f = f0 + tx;
    if (t < Tt && f < Ff) {
      size_t idx = (((size_t)b * Tt + t) * Cc + c) * Ff + f;
      tile[ty + 8 * ii][tx] = make_float2(in_re[idx], in_im[idx]);
    }
  }
  __syncthreads();
#pragma unroll
  for (int ii = 0; ii < 4; ++ii) {
    int f = f0 + ty + 8 * ii, t = t0 + tx;
    if (f < Ff && t < Tt) {
      size_t o = (((size_t)b * Ff + f) * Cc + c) * Tt + t;
      Yt[o] = tile[tx][ty + 8 * ii];
    }
  }
}

// One block per (b,f): full 2-iteration WPE.
__global__ __launch_bounds__(256) void k_wpe(const float2* __restrict__ Yt,
                                             float2* __restrict__ enh,
                                             const float* __restrict__ in_re,
                                             const float* __restrict__ in_im,
                                             const int* __restrict__ ilens,
                                             float* __restrict__ out_re,
                                             float* __restrict__ out_im,
                                             int load_direct, int store_direct) {
  __shared__ float2 Yl[Cc][TP];        // 8 x 601 complex
  __shared__ float2 RP[KC][NC + 1];    // [R | P] 40 x 48 (+pad)
  __shared__ float wl[Tt];             // 1/power weights

  int bf = blockIdx.x;
  int b = bf / Ff, f = bf % Ff;
  int tid = threadIdx.x;

  // ---- stage Y into LDS
  if (!load_direct) {
    const float4* Yg = (const float4*)(Yt + (size_t)bf * (Cc * Tt));
    for (int i = tid; i < Cc * Tt / 2; i += 256) {
      float4 v = Yg[i];
      int c = i / (Tt / 2), t2 = (i % (Tt / 2)) * 2;
      Yl[c][t2]     = make_float2(v.x, v.y);
      Yl[c][t2 + 1] = make_float2(v.z, v.w);
    }
  } else {
    for (int i = tid; i < Cc * Tt; i += 256) {
      int c = i / Tt, t = i % Tt;
      size_t idx = (((size_t)b * Tt + t) * Cc + c) * Ff + f;
      Yl[c][t] = make_float2(in_re[idx], in_im[idx]);
    }
  }
  __syncthreads();

  const float2* YlF = &Yl[0][0];
  int ty = tid >> 4, tx = tid & 15;

  // row/col flat-offsets for the R|P accumulation:
  // row i=k*8+d -> w*conj(Y[d][t+4-k]); col j<40 -> Y[d][t+4-k]; col 40+e -> Y[e][t+7]
  int roff[3]; bool rv[3];
#pragma unroll
  for (int a = 0; a < 3; ++a) {
    int r = ty + 16 * a;
    rv[a] = (r < KC);
    int rr = rv[a] ? r : 0;
    int k = rr >> 3, d = rr & 7;
    roff[a] = d * TP + 4 - k;
  }
  int coff[3];
#pragma unroll
  for (int bb = 0; bb < 3; ++bb) {
    int cc = tx + 16 * bb;
    if (cc < KC) { int k = cc >> 3, d = cc & 7; coff[bb] = d * TP + 4 - k; }
    else         { int e = cc - KC;             coff[bb] = e * TP + 7; }
  }

  for (int iter = 0; iter < 3; ++iter) {
    // ---- weights from power (iter 0: from Y; iter 1: from enhanced_0);
    //      iter 2: compute enhanced_1 and store.
    if (iter == 0) {
      for (int t = tid; t < Tt; t += 256) {
        float s = 0.f;
#pragma unroll
        for (int c = 0; c < Cc; ++c) { float2 y = Yl[c][t]; s += y.x*y.x + y.y*y.y; }
        wl[t] = 1.0f / fmaxf(s * 0.125f, EPSF);
      }
    } else {
      for (int t = tid; t < Tt; t += 256) {
        float2 acc[Cc];
#pragma unroll
        for (int e = 0; e < Cc; ++e) acc[e] = Yl[e][t];
        for (int p = 0; p < TAPS; ++p) {
          int ts = t - DELAY - p;
          if (ts < 0) break;   // zero-padded region
#pragma unroll
          for (int d = 0; d < Cc; ++d) {
            float2 u = Yl[d][ts];
            int j = p * Cc + d;
#pragma unroll
            for (int e = 0; e < Cc; ++e) {
              float2 g = RP[j][KC + e];   // filter X[j][e] from the solve
              acc[e].x -= g.x*u.x - g.y*u.y;
              acc[e].y -= g.x*u.y + g.y*u.x;
            }
          }
        }
        if (iter == 1) {
          float s = 0.f;
#pragma unroll
          for (int e = 0; e < Cc; ++e) s += acc[e].x*acc[e].x + acc[e].y*acc[e].y;
          wl[t] = 1.0f / fmaxf(s * 0.125f, EPSF);
        } else {
          if (!store_direct) {
            float2* Eg = enh + (size_t)bf * (Cc * Tt);
#pragma unroll
            for (int e = 0; e < Cc; ++e) Eg[e * Tt + t] = acc[e];
          } else {
            int il = ilens[b];
            bool live = (t < il);
#pragma unroll
            for (int e = 0; e < Cc; ++e) {
              float2 v = live ? acc[e] : make_float2(0.f, 0.f);
              size_t idx = (((size_t)b * Tt + t) * Cc + e) * Ff + f;
              out_re[idx] = v.x;
              out_im[idx] = v.y;
            }
          }
        }
      }
    }
    if (iter == 2) break;
    __syncthreads();

    // ---- accumulate [R | P]: racc[a][bb] = sum_t w_t*conj(v_t[row]) * bcol_t
    float2 racc[3][3];
#pragma unroll
    for (int a = 0; a < 3; ++a)
#pragma unroll
      for (int bb = 0; bb < 3; ++bb) racc[a][bb] = make_float2(0.f, 0.f);

    for (int t = 0; t < TQ; ++t) {
      float w = wl[t + DELAY + TAPS - 1];
      float2 bv[3];
#pragma unroll
      for (int bb = 0; bb < 3; ++bb) bv[bb] = YlF[coff[bb] + t];
#pragma unroll
      for (int a = 0; a < 3; ++a) {
        if (!rv[a]) continue;
        float2 y = YlF[roff[a] + t];
        float2 av = make_float2(w * y.x, -w * y.y);   // w * conj(v)
#pragma unroll
        for (int bb = 0; bb < 3; ++bb) {
          float2 pr = cmul2(av, bv[bb]);
          racc[a][bb].x += pr.x;
          racc[a][bb].y += pr.y;
        }
      }
    }
#pragma unroll
    for (int a = 0; a < 3; ++a) {
      if (!rv[a]) continue;
      int r = ty + 16 * a;
#pragma unroll
      for (int bb = 0; bb < 3; ++bb) RP[r][tx + 16 * bb] = racc[a][bb];
    }
    __syncthreads();

    // ---- regularize diagonal
    if (tid < KC) RP[tid][tid].x += EPSF;
    __syncthreads();

    // ---- Gauss-Jordan on [R | P] (HPD -> no pivoting); cols 40..47 become X=R^-1 P
    for (int j = 0; j < KC; ++j) {
      float2 pv = RP[j][j];
      float idn = 1.0f / (pv.x*pv.x + pv.y*pv.y);
      float2 ip = make_float2(pv.x * idn, -pv.y * idn);   // 1/pivot
      for (int k = j + 1 + tid; k < NC; k += 256)
        RP[j][k] = cmul2(RP[j][k], ip);
      __syncthreads();
      int ncols = NC - 1 - j;
      int tot = (KC - 1) * ncols;
      for (int idx = tid; idx < tot; idx += 256) {
        int i = idx / ncols;
        if (i >= j) ++i;                 // all rows except j
        int k = j + 1 + idx % ncols;
        float2 lij = RP[i][j];
        float2 s = cmul2(lij, RP[j][k]);
        RP[i][k].x -= s.x;
        RP[i][k].y -= s.y;
      }
      __syncthreads();
    }
  }
}

// (B,F,C,T) float2 -> masked (B,T,C,F) re/im planes
__global__ __launch_bounds__(256) void k_tout(const float2* __restrict__ enh,
                                              const int* __restrict__ ilens,
                                              float* __restrict__ out_re,
                                              float* __restrict__ out_im) {
  __shared__ float2 tile[32][33];
  int t0 = blockIdx.x * 32, f0 = blockIdx.y * 32;
  int b = blockIdx.z >> 3, c = blockIdx.z & 7;
  int tx = threadIdx.x & 31, ty = threadIdx.x >> 5;
#pragma unroll
  for (int ii = 0; ii < 4; ++ii) {
    int f = f0 + ty + 8 * ii, t = t0 + tx;
    if (f < Ff && t < Tt)
      tile[ty + 8 * ii][tx] = enh[(((size_t)b * Ff + f) * Cc + c) * Tt + t];
  }
  __syncthreads();
  int il = ilens[b];
#pragma unroll
  for (int ii = 0; ii < 4; ++ii) {
    int t = t0 + ty + 8 * ii, f = f0 + tx;
    if (t < Tt && f < Ff) {
      float2 v = tile[tx][ty + 8 * ii];
      if (t >= il) v = make_float2(0.f, 0.f);
      size_t idx = (((size_t)b * Tt + t) * Cc + c) * Ff + f;
      out_re[idx] = v.x;
      out_im[idx] = v.y;
    }
  }
}

extern "C" void kernel_launch(void* const* d_in, const int* in_sizes, int n_in,
                              void* d_out, int out_size, void* d_ws, size_t ws_size,
                              hipStream_t stream) {
  const float* in_re = (const float*)d_in[0];
  const float* in_im = (const float*)d_in[1];
  const int* ilens = (const int*)d_in[2];
  float* out_re = (float*)d_out;
  float* out_im = out_re + NTOT;

  size_t ybytes = (size_t)Bb * Ff * Cc * Tt * sizeof(float2);  // 78,950,400 B
  int have_yt  = ws_size >= ybytes;
  int have_enh = ws_size >= 2 * ybytes;
  float2* Yt  = (float2*)d_ws;
  float2* enh = (float2*)((char*)d_ws + ybytes);

  if (have_yt) {
    dim3 g((Ff + 31) / 32, (Tt + 31) / 32, Bb * Cc);
    k_tin<<<g, dim3(256), 0, stream>>>(in_re, in_im, Yt);
  }
  {
    dim3 g(Bb * Ff);
    k_wpe<<<g, dim3(256), 0, stream>>>(Yt, enh, in_re, in_im, ilens,
                                       out_re, out_im,
                                       have_yt ? 0 : 1, have_enh ? 0 : 1);
  }
  if (have_enh) {
    dim3 g((Tt + 31) / 32, (Ff + 31) / 32, Bb * Cc);
    k_tout<<<g, dim3(256), 0, stream>>>(enh, ilens, out_re, out_im);
  }
}

// Round 2
// 1266.680 us; speedup vs baseline: 1.7400x; 1.7400x over previous
//
#include <hip/hip_runtime.h>
#include <hip/hip_bf16.h>

#define Bb 8
#define Tt 600
#define Cc 8
#define Ff 257
#define TAPS 5
#define DELAY 3
#define KC 40            // TAPS*C
#define NC 48            // KC + C (R columns | P columns)
#define TQ 593           // T - DELAY - TAPS + 1
#define TP 602           // LDS row stride (float2): 2*602 mod 32 = 20 -> conflict-free col set
#define EPSF 1e-10f
#define NTOT (Bb*Tt*Cc*Ff)   // 9,868,800

__device__ __forceinline__ float2 cmul2(float2 a, float2 b) {
  return make_float2(a.x*b.x - a.y*b.y, a.x*b.y + a.y*b.x);
}

// conj(a)*b accumulate, 4-FMA form (ax,ay = w*y.x, w*y.y)
#define CMAC(acc, ax, ay, b)                    \
  acc.x = fmaf(ax, b.x, acc.x);                 \
  acc.x = fmaf(ay, b.y, acc.x);                 \
  acc.y = fmaf(ax, b.y, acc.y);                 \
  acc.y = fmaf(-(ay), b.x, acc.y);

// (B,T,C,F) re/im planes -> (B,F,C,T) interleaved float2
__global__ __launch_bounds__(256) void k_tin(const float* __restrict__ in_re,
                                             const float* __restrict__ in_im,
                                             float2* __restrict__ Yt) {
  __shared__ float2 tile[32][33];
  int f0 = blockIdx.x * 32, t0 = blockIdx.y * 32;
  int b = blockIdx.z >> 3, c = blockIdx.z & 7;
  int tx = threadIdx.x & 31, ty = threadIdx.x >> 5;
#pragma unroll
  for (int ii = 0; ii < 4; ++ii) {
    int t = t0 + ty + 8 * ii, f = f0 + tx;
    if (t < Tt && f < Ff) {
      size_t idx = (((size_t)b * Tt + t) * Cc + c) * Ff + f;
      tile[ty + 8 * ii][tx] = make_float2(in_re[idx], in_im[idx]);
    }
  }
  __syncthreads();
#pragma unroll
  for (int ii = 0; ii < 4; ++ii) {
    int f = f0 + ty + 8 * ii, t = t0 + tx;
    if (f < Ff && t < Tt) {
      size_t o = (((size_t)b * Ff + f) * Cc + c) * Tt + t;
      Yt[o] = tile[tx][ty + 8 * ii];
    }
  }
}

// One block (512 thr) per (b,f): full 2-iteration WPE. K-split-2 accumulation.
__global__ __launch_bounds__(512, 4) void k_wpe(const float2* __restrict__ Yt,
                                                float2* __restrict__ enh,
                                                const float* __restrict__ in_re,
                                                const float* __restrict__ in_im,
                                                const int* __restrict__ ilens,
                                                float* __restrict__ out_re,
                                                float* __restrict__ out_im,
                                                int load_direct, int store_direct) {
  __shared__ float2 Yl[Cc][TP];        // 8 x 602 complex = 38528 B
  __shared__ float2 RP[KC][NC + 1];    // [R | P] 40 x 48 (+pad) = 15680 B
  __shared__ float wl[Tt];             // 2400 B   -> total 56608 B

  int bf = blockIdx.x;
  int b = bf / Ff, f = bf % Ff;
  int tid = threadIdx.x;               // 0..511
  int half = tid >> 8;                 // K-split half
  int stid = tid & 255;
  int ty = stid >> 4, tx = stid & 15;

  // ---- stage Y into LDS
  if (!load_direct) {
    const float4* Yg = (const float4*)(Yt + (size_t)bf * (Cc * Tt));
    for (int i = tid; i < Cc * Tt / 2; i += 512) {
      float4 v = Yg[i];
      int c = i / (Tt / 2), t2 = (i % (Tt / 2)) * 2;
      *(float4*)&Yl[c][t2] = v;        // 16B-aligned: 602*c + t2 is even
    }
  } else {
    for (int i = tid; i < Cc * Tt; i += 512) {
      int c = i / Tt, t = i % Tt;
      size_t idx = (((size_t)b * Tt + t) * Cc + c) * Ff + f;
      Yl[c][t] = make_float2(in_re[idx], in_im[idx]);
    }
  }
  __syncthreads();

  const float2* YlF = &Yl[0][0];

  // rows r = ty + 16a (a=0,1 always valid; a=2 valid iff ty<8 -> wave-uniform)
  bool rv2 = (ty < 8);
  int roff[3];
#pragma unroll
  for (int a = 0; a < 3; ++a) {
    int r = ty + 16 * a;
    if (a == 2 && !rv2) r = 0;
    int k = r >> 3, d = r & 7;
    roff[a] = d * TP + 4 - k;
  }
  int coff[3];
#pragma unroll
  for (int bb = 0; bb < 3; ++bb) {
    int cc = tx + 16 * bb;
    if (cc < KC) { int k = cc >> 3, d = cc & 7; coff[bb] = d * TP + 4 - k; }
    else         { int e = cc - KC;             coff[bb] = e * TP + 7; }
  }

  int tA = half ? 297 : 0;
  int tB = half ? TQ : 297;

  for (int iter = 0; iter < 3; ++iter) {
    // ---- weights (iter 0 from Y; iter 1 from enhanced_0); iter 2: store result
    if (iter == 0) {
      for (int t = tid; t < Tt; t += 512) {
        float s = 0.f;
#pragma unroll
        for (int c = 0; c < Cc; ++c) { float2 y = Yl[c][t]; s += y.x*y.x + y.y*y.y; }
        wl[t] = 1.0f / fmaxf(s * 0.125f, EPSF);
      }
    } else {
      for (int t = tid; t < Tt; t += 512) {
        float2 acc[Cc];
#pragma unroll
        for (int e = 0; e < Cc; ++e) acc[e] = Yl[e][t];
        for (int p = 0; p < TAPS; ++p) {
          int ts = t - DELAY - p;
          if (ts < 0) break;   // zero-padded region
#pragma unroll
          for (int d = 0; d < Cc; ++d) {
            float2 u = Yl[d][ts];
            int j = p * Cc + d;
#pragma unroll
            for (int e = 0; e < Cc; ++e) {
              float2 g = RP[j][KC + e];   // filter X[j][e] from the solve
              acc[e].x -= g.x*u.x - g.y*u.y;
              acc[e].y -= g.x*u.y + g.y*u.x;
            }
          }
        }
        if (iter == 1) {
          float s = 0.f;
#pragma unroll
          for (int e = 0; e < Cc; ++e) s += acc[e].x*acc[e].x + acc[e].y*acc[e].y;
          wl[t] = 1.0f / fmaxf(s * 0.125f, EPSF);
        } else {
          if (!store_direct) {
            float2* Eg = enh + (size_t)bf * (Cc * Tt);
#pragma unroll
            for (int e = 0; e < Cc; ++e) Eg[e * Tt + t] = acc[e];
          } else {
            int il = ilens[b];
            bool live = (t < il);
#pragma unroll
            for (int e = 0; e < Cc; ++e) {
              float2 v = live ? acc[e] : make_float2(0.f, 0.f);
              size_t idx = (((size_t)b * Tt + t) * Cc + e) * Ff + f;
              out_re[idx] = v.x;
              out_im[idx] = v.y;
            }
          }
        }
      }
    }
    if (iter == 2) break;
    __syncthreads();

    // ---- accumulate [R | P] over this half's t-range: 3x3 register tile
    float2 racc[3][3];
#pragma unroll
    for (int a = 0; a < 3; ++a)
#pragma unroll
      for (int bb = 0; bb < 3; ++bb) racc[a][bb] = make_float2(0.f, 0.f);

#pragma unroll 2
    for (int t = tA; t < tB; ++t) {
      float w = wl[t + DELAY + TAPS - 1];
      float2 bv0 = YlF[coff[0] + t];
      float2 bv1 = YlF[coff[1] + t];
      float2 bv2 = YlF[coff[2] + t];
      float2 y0 = YlF[roff[0] + t];
      float2 y1 = YlF[roff[1] + t];
      float a0x = w * y0.x, a0y = w * y0.y;
      float a1x = w * y1.x, a1y = w * y1.y;
      CMAC(racc[0][0], a0x, a0y, bv0);
      CMAC(racc[0][1], a0x, a0y, bv1);
      CMAC(racc[0][2], a0x, a0y, bv2);
      CMAC(racc[1][0], a1x, a1y, bv0);
      CMAC(racc[1][1], a1x, a1y, bv1);
      CMAC(racc[1][2], a1x, a1y, bv2);
      if (rv2) {
        float2 y2 = YlF[roff[2] + t];
        float a2x = w * y2.x, a2y = w * y2.y;
        CMAC(racc[2][0], a2x, a2y, bv0);
        CMAC(racc[2][1], a2x, a2y, bv1);
        CMAC(racc[2][2], a2x, a2y, bv2);
      }
    }

    // half 0 writes, half 1 accumulates on top (each (r,c) touched by exactly
    // one thread per half)
    if (half == 0) {
#pragma unroll
      for (int a = 0; a < 3; ++a) {
        if (a == 2 && !rv2) continue;
        int r = ty + 16 * a;
#pragma unroll
        for (int bb = 0; bb < 3; ++bb) RP[r][tx + 16 * bb] = racc[a][bb];
      }
    }
    __syncthreads();
    if (half == 1) {
#pragma unroll
      for (int a = 0; a < 3; ++a) {
        if (a == 2 && !rv2) continue;
        int r = ty + 16 * a;
#pragma unroll
        for (int bb = 0; bb < 3; ++bb) {
          float2 v = RP[r][tx + 16 * bb];
          v.x += racc[a][bb].x; v.y += racc[a][bb].y;
          RP[r][tx + 16 * bb] = v;
        }
      }
    }
    __syncthreads();

    // ---- regularize diagonal
    if (tid < KC) RP[tid][tid].x += EPSF;
    __syncthreads();

    // ---- Gauss-Jordan on [R | P] (HPD -> no pivoting); cols 40..47 become X=R^-1 P
    for (int j = 0; j < KC; ++j) {
      float2 pv = RP[j][j];
      float idn = 1.0f / (pv.x*pv.x + pv.y*pv.y);
      float2 ip = make_float2(pv.x * idn, -pv.y * idn);   // 1/pivot
      for (int k = j + 1 + tid; k < NC; k += 512)
        RP[j][k] = cmul2(RP[j][k], ip);
      __syncthreads();
      int ncols = NC - 1 - j;
      int tot = (KC - 1) * ncols;
      for (int idx = tid; idx < tot; idx += 512) {
        int i = idx / ncols;
        if (i >= j) ++i;                 // all rows except j
        int k = j + 1 + idx % ncols;
        float2 lij = RP[i][j];
        float2 s = cmul2(lij, RP[j][k]);
        RP[i][k].x -= s.x;
        RP[i][k].y -= s.y;
      }
      __syncthreads();
    }
  }
}

// (B,F,C,T) float2 -> masked (B,T,C,F) re/im planes
__global__ __launch_bounds__(256) void k_tout(const float2* __restrict__ enh,
                                              const int* __restrict__ ilens,
                                              float* __restrict__ out_re,
                                              float* __restrict__ out_im) {
  __shared__ float2 tile[32][33];
  int t0 = blockIdx.x * 32, f0 = blockIdx.y * 32;
  int b = blockIdx.z >> 3, c = blockIdx.z & 7;
  int tx = threadIdx.x & 31, ty = threadIdx.x >> 5;
#pragma unroll
  for (int ii = 0; ii < 4; ++ii) {
    int f = f0 + ty + 8 * ii, t = t0 + tx;
    if (f < Ff && t < Tt)
      tile[ty + 8 * ii][tx] = enh[(((size_t)b * Ff + f) * Cc + c) * Tt + t];
  }
  __syncthreads();
  int il = ilens[b];
#pragma unroll
  for (int ii = 0; ii < 4; ++ii) {
    int t = t0 + ty + 8 * ii, f = f0 + tx;
    if (t < Tt && f < Ff) {
      float2 v = tile[tx][ty + 8 * ii];
      if (t >= il) v = make_float2(0.f, 0.f);
      size_t idx = (((size_t)b * Tt + t) * Cc + c) * Ff + f;
      out_re[idx] = v.x;
      out_im[idx] = v.y;
    }
  }
}

extern "C" void kernel_launch(void* const* d_in, const int* in_sizes, int n_in,
                              void* d_out, int out_size, void* d_ws, size_t ws_size,
                              hipStream_t stream) {
  const float* in_re = (const float*)d_in[0];
  const float* in_im = (const float*)d_in[1];
  const int* ilens = (const int*)d_in[2];
  float* out_re = (float*)d_out;
  float* out_im = out_re + NTOT;

  size_t ybytes = (size_t)Bb * Ff * Cc * Tt * sizeof(float2);  // 78,950,400 B
  int have_yt  = ws_size >= ybytes;
  int have_enh = ws_size >= 2 * ybytes;
  float2* Yt  = (float2*)d_ws;
  float2* enh = (float2*)((char*)d_ws + ybytes);

  if (have_yt) {
    dim3 g((Ff + 31) / 32, (Tt + 31) / 32, Bb * Cc);
    k_tin<<<g, dim3(256), 0, stream>>>(in_re, in_im, Yt);
  }
  {
    dim3 g(Bb * Ff);
    k_wpe<<<g, dim3(512), 0, stream>>>(Yt, enh, in_re, in_im, ilens,
                                       out_re, out_im,
                                       have_yt ? 0 : 1, have_enh ? 0 : 1);
  }
  if (have_enh) {
    dim3 g((Tt + 31) / 32, (Ff + 31) / 32, Bb * Cc);
    k_tout<<<g, dim3(256), 0, stream>>>(enh, ilens, out_re, out_im);
  }
}

// Round 3
// 1203.045 us; speedup vs baseline: 1.8320x; 1.0529x over previous
//
#include <hip/hip_runtime.h>
#include <hip/hip_bf16.h>

#define Bb 8
#define Tt 600
#define Cc 8
#define Ff 257
#define TAPS 5
#define DELAY 3
#define KC 40            // TAPS*C
#define NC 48            // KC + C (R columns | P columns)
#define RPW 52           // RP row stride (float2): 104 dwords % 32 = 8 -> 2-way max (free)
#define TQ 593           // T - DELAY - TAPS + 1
#define TP 602           // Y LDS row stride (float2): conflict-free for channel-strided access
#define EPSF 1e-10f
#define NTOT (Bb*Tt*Cc*Ff)   // 9,868,800

__device__ __forceinline__ float2 cmul2(float2 a, float2 b) {
  return make_float2(a.x*b.x - a.y*b.y, a.x*b.y + a.y*b.x);
}

// acc += conj(a)*b with a pre-scaled: (ax,ay) = (w*y.x, w*y.y)
#define CMAC(acc, ax, ay, b)                    \
  acc.x = fmaf(ax, b.x, acc.x);                 \
  acc.x = fmaf(ay, b.y, acc.x);                 \
  acc.y = fmaf(ax, b.y, acc.y);                 \
  acc.y = fmaf(-(ay), b.x, acc.y);

// (B,T,C,F) re/im planes -> (B,F,C,T) interleaved float2
__global__ __launch_bounds__(256) void k_tin(const float* __restrict__ in_re,
                                             const float* __restrict__ in_im,
                                             float2* __restrict__ Yt) {
  __shared__ float2 tile[32][33];
  int f0 = blockIdx.x * 32, t0 = blockIdx.y * 32;
  int b = blockIdx.z >> 3, c = blockIdx.z & 7;
  int tx = threadIdx.x & 31, ty = threadIdx.x >> 5;
#pragma unroll
  for (int ii = 0; ii < 4; ++ii) {
    int t = t0 + ty + 8 * ii, f = f0 + tx;
    if (t < Tt && f < Ff) {
      size_t idx = (((size_t)b * Tt + t) * Cc + c) * Ff + f;
      tile[ty + 8 * ii][tx] = make_float2(in_re[idx], in_im[idx]);
    }
  }
  __syncthreads();
#pragma unroll
  for (int ii = 0; ii < 4; ++ii) {
    int f = f0 + ty + 8 * ii, t = t0 + tx;
    if (f < Ff && t < Tt) {
      size_t o = (((size_t)b * Ff + f) * Cc + c) * Tt + t;
      Yt[o] = tile[tx][ty + 8 * ii];
    }
  }
}

// Unrolled accumulation body; u is a literal 0..4 so all %5 indices fold.
#define ABODY(u) do {                                                     \
  float2 ynd = Yd[tb + (u) + 4];                                          \
  float2 yne = Ye[tb + (u) + 4];                                          \
  float2 yep = Ye[tb + (u) + 7];                                          \
  float w = wl[tb + (u) + 7];                                             \
  wd[((u)+4)%5] = ynd; we[((u)+4)%5] = yne;                               \
  float ax[5], ay[5];                                                     \
  _Pragma("unroll")                                                       \
  for (int k = 0; k < 5; ++k) {                                           \
    float2 yr = wd[((u)+4-k)%5]; ax[k] = w*yr.x; ay[k] = w*yr.y;          \
  }                                                                       \
  _Pragma("unroll")                                                       \
  for (int l = 0; l < 5; ++l) {                                           \
    float2 yc = we[((u)+4-l)%5];                                          \
    _Pragma("unroll")                                                     \
    for (int k = 0; k < 5; ++k) { CMAC(rac[k][l], ax[k], ay[k], yc); }    \
  }                                                                       \
  _Pragma("unroll")                                                       \
  for (int k = 0; k < 5; ++k) { CMAC(pac[k], ax[k], ay[k], yep); }        \
} while (0)

// One block (512 thr) per (b,f): full 2-iteration WPE.
// Accumulation: 64-thread groups, thread=(d,e) owns 5x5 R-tile + 5 P via
// register sliding windows; 8-way t-split, sequential LDS merge.
__global__ __launch_bounds__(512, 4) void k_wpe(const float2* __restrict__ Yt,
                                                float2* __restrict__ enh,
                                                const float* __restrict__ in_re,
                                                const float* __restrict__ in_im,
                                                const int* __restrict__ ilens,
                                                float* __restrict__ out_re,
                                                float* __restrict__ out_im,
                                                int load_direct, int store_direct) {
  __shared__ float2 Yl[Cc][TP];        // 8 x 602 complex = 38528 B
  __shared__ float2 RP[KC][RPW];       // [R | P] 40 x 52      = 16640 B
  __shared__ float wl[Tt];             // 2400 B   -> total 57568 B

  int bf = blockIdx.x;
  int b = bf / Ff, f = bf % Ff;
  int tid = threadIdx.x;               // 0..511
  int group = tid >> 6;                // t-split group (wave)
  int lane = tid & 63;
  int d = lane & 7;                    // row channel
  int e = lane >> 3;                   // col channel

  // ---- stage Y into LDS
  if (!load_direct) {
    const float4* Yg = (const float4*)(Yt + (size_t)bf * (Cc * Tt));
    for (int i = tid; i < Cc * Tt / 2; i += 512) {
      float4 v = Yg[i];
      int c = i / (Tt / 2), t2 = (i % (Tt / 2)) * 2;
      *(float4*)&Yl[c][t2] = v;        // 16B aligned: 602*c + t2 even
    }
  } else {
    for (int i = tid; i < Cc * Tt; i += 512) {
      int c = i / Tt, t = i % Tt;
      size_t idx = (((size_t)b * Tt + t) * Cc + c) * Ff + f;
      Yl[c][t] = make_float2(in_re[idx], in_im[idx]);
    }
  }
  __syncthreads();

  const float2* Yd = &Yl[d][0];
  const float2* Ye = &Yl[e][0];

  int tA = (TQ * group) >> 3;
  int tB = (TQ * (group + 1)) >> 3;

  for (int iter = 0; iter < 3; ++iter) {
    // ---- weights (iter 0 from Y; iter 1 from enhanced_0); iter 2: store result
    if (iter == 0) {
      for (int t = tid; t < Tt; t += 512) {
        float s = 0.f;
#pragma unroll
        for (int c = 0; c < Cc; ++c) { float2 y = Yl[c][t]; s += y.x*y.x + y.y*y.y; }
        wl[t] = 1.0f / fmaxf(s * 0.125f, EPSF);
      }
    } else {
      for (int t = tid; t < Tt; t += 512) {
        float2 acc[Cc];
#pragma unroll
        for (int ee = 0; ee < Cc; ++ee) acc[ee] = Yl[ee][t];
        for (int p = 0; p < TAPS; ++p) {
          int ts = t - DELAY - p;
          if (ts < 0) break;   // zero-padded region
#pragma unroll
          for (int dd = 0; dd < Cc; ++dd) {
            float2 u = Yl[dd][ts];
            int j = p * Cc + dd;
#pragma unroll
            for (int ee = 0; ee < Cc; ++ee) {
              float2 g = RP[j][KC + ee];   // filter X[j][e] from the solve
              acc[ee].x -= g.x*u.x - g.y*u.y;
              acc[ee].y -= g.x*u.y + g.y*u.x;
            }
          }
        }
        if (iter == 1) {
          float s = 0.f;
#pragma unroll
          for (int ee = 0; ee < Cc; ++ee) s += acc[ee].x*acc[ee].x + acc[ee].y*acc[ee].y;
          wl[t] = 1.0f / fmaxf(s * 0.125f, EPSF);
        } else {
          if (!store_direct) {
            float2* Eg = enh + (size_t)bf * (Cc * Tt);
#pragma unroll
            for (int ee = 0; ee < Cc; ++ee) Eg[ee * Tt + t] = acc[ee];
          } else {
            int il = ilens[b];
            bool live = (t < il);
#pragma unroll
            for (int ee = 0; ee < Cc; ++ee) {
              float2 v = live ? acc[ee] : make_float2(0.f, 0.f);
              size_t idx = (((size_t)b * Tt + t) * Cc + ee) * Ff + f;
              out_re[idx] = v.x;
              out_im[idx] = v.y;
            }
          }
        }
      }
    }
    if (iter == 2) break;
    __syncthreads();

    // ---- accumulate [R | P]: per-thread 5x5+5 tile, register sliding windows
    float2 rac[5][5], pac[5];
#pragma unroll
    for (int k = 0; k < 5; ++k) {
#pragma unroll
      for (int l = 0; l < 5; ++l) rac[k][l] = make_float2(0.f, 0.f);
      pac[k] = make_float2(0.f, 0.f);
    }

    float2 wd[5], we[5];
#pragma unroll
    for (int i = 0; i < 4; ++i) { wd[i] = Yd[tA + i]; we[i] = Ye[tA + i]; }

    int tb = tA;
    for (; tb + 5 <= tB; tb += 5) {
      ABODY(0); ABODY(1); ABODY(2); ABODY(3); ABODY(4);
    }
    for (int t = tb; t < tB; ++t) {    // tail (<=4 iters): read fresh
      float2 yep = Ye[t + 7];
      float w = wl[t + 7];
      float ax[5], ay[5];
#pragma unroll
      for (int k = 0; k < 5; ++k) {
        float2 yr = Yd[t + 4 - k]; ax[k] = w*yr.x; ay[k] = w*yr.y;
      }
#pragma unroll
      for (int l = 0; l < 5; ++l) {
        float2 yc = Ye[t + 4 - l];
#pragma unroll
        for (int k = 0; k < 5; ++k) { CMAC(rac[k][l], ax[k], ay[k], yc); }
      }
#pragma unroll
      for (int k = 0; k < 5; ++k) { CMAC(pac[k], ax[k], ay[k], yep); }
    }

    // ---- merge the 8 group partials into RP (wave-uniform branch per pass)
    for (int gpass = 0; gpass < 8; ++gpass) {
      if (group == gpass) {
        if (gpass == 0) {
#pragma unroll
          for (int k = 0; k < 5; ++k) {
#pragma unroll
            for (int l = 0; l < 5; ++l) RP[k*8+d][l*8+e] = rac[k][l];
            RP[k*8+d][KC+e] = pac[k];
          }
        } else {
#pragma unroll
          for (int k = 0; k < 5; ++k) {
#pragma unroll
            for (int l = 0; l < 5; ++l) {
              float2 v = RP[k*8+d][l*8+e];
              v.x += rac[k][l].x; v.y += rac[k][l].y;
              RP[k*8+d][l*8+e] = v;
            }
            float2 v = RP[k*8+d][KC+e];
            v.x += pac[k].x; v.y += pac[k].y;
            RP[k*8+d][KC+e] = v;
          }
        }
      }
      __syncthreads();
    }

    // ---- regularize diagonal
    if (tid < KC) RP[tid][tid].x += EPSF;
    __syncthreads();

    // ---- Gauss-Jordan on [R | P] (HPD -> no pivoting); cols 40..47 become X=R^-1 P
    for (int j = 0; j < KC; ++j) {
      float2 pv = RP[j][j];
      float idn = 1.0f / (pv.x*pv.x + pv.y*pv.y);
      float2 ip = make_float2(pv.x * idn, -pv.y * idn);   // 1/pivot
      for (int k = j + 1 + tid; k < NC; k += 512)
        RP[j][k] = cmul2(RP[j][k], ip);
      __syncthreads();
      int ncols = NC - 1 - j;
      int tot = (KC - 1) * ncols;
      for (int idx = tid; idx < tot; idx += 512) {
        int i = idx / ncols;
        if (i >= j) ++i;                 // all rows except j
        int k = j + 1 + idx % ncols;
        float2 lij = RP[i][j];
        float2 s = cmul2(lij, RP[j][k]);
        RP[i][k].x -= s.x;
        RP[i][k].y -= s.y;
      }
      __syncthreads();
    }
  }
}

// (B,F,C,T) float2 -> masked (B,T,C,F) re/im planes
__global__ __launch_bounds__(256) void k_tout(const float2* __restrict__ enh,
                                              const int* __restrict__ ilens,
                                              float* __restrict__ out_re,
                                              float* __restrict__ out_im) {
  __shared__ float2 tile[32][33];
  int t0 = blockIdx.x * 32, f0 = blockIdx.y * 32;
  int b = blockIdx.z >> 3, c = blockIdx.z & 7;
  int tx = threadIdx.x & 31, ty = threadIdx.x >> 5;
#pragma unroll
  for (int ii = 0; ii < 4; ++ii) {
    int f = f0 + ty + 8 * ii, t = t0 + tx;
    if (f < Ff && t < Tt)
      tile[ty + 8 * ii][tx] = enh[(((size_t)b * Ff + f) * Cc + c) * Tt + t];
  }
  __syncthreads();
  int il = ilens[b];
#pragma unroll
  for (int ii = 0; ii < 4; ++ii) {
    int t = t0 + ty + 8 * ii, f = f0 + tx;
    if (t < Tt && f < Ff) {
      float2 v = tile[tx][ty + 8 * ii];
      if (t >= il) v = make_float2(0.f, 0.f);
      size_t idx = (((size_t)b * Tt + t) * Cc + c) * Ff + f;
      out_re[idx] = v.x;
      out_im[idx] = v.y;
    }
  }
}

extern "C" void kernel_launch(void* const* d_in, const int* in_sizes, int n_in,
                              void* d_out, int out_size, void* d_ws, size_t ws_size,
                              hipStream_t stream) {
  const float* in_re = (const float*)d_in[0];
  const float* in_im = (const float*)d_in[1];
  const int* ilens = (const int*)d_in[2];
  float* out_re = (float*)d_out;
  float* out_im = out_re + NTOT;

  size_t ybytes = (size_t)Bb * Ff * Cc * Tt * sizeof(float2);  // 78,950,400 B
  int have_yt  = ws_size >= ybytes;
  int have_enh = ws_size >= 2 * ybytes;
  float2* Yt  = (float2*)d_ws;
  float2* enh = (float2*)((char*)d_ws + ybytes);

  if (have_yt) {
    dim3 g((Ff + 31) / 32, (Tt + 31) / 32, Bb * Cc);
    k_tin<<<g, dim3(256), 0, stream>>>(in_re, in_im, Yt);
  }
  {
    dim3 g(Bb * Ff);
    k_wpe<<<g, dim3(512), 0, stream>>>(Yt, enh, in_re, in_im, ilens,
                                       out_re, out_im,
                                       have_yt ? 0 : 1, have_enh ? 0 : 1);
  }
  if (have_enh) {
    dim3 g((Tt + 31) / 32, (Ff + 31) / 32, Bb * Cc);
    k_tout<<<g, dim3(256), 0, stream>>>(enh, ilens, out_re, out_im);
  }
}